// Round 1
// 1485.122 us; speedup vs baseline: 1.1221x; 1.1221x over previous
//
#include <hip/hip_runtime.h>
#include <math.h>

// ---------------------------------------------------------------------------
// BDH forward, MI355X. Round 10 = round 9 + double-buffered LDS (T3 "minimum
// 2-phase") in gemm_bt for ALL modes. Round-9 counters: scores gemm at 12.5%
// HBM, 19% MfmaUtil, 17% occupancy => latency-bound (576 blocks = 2.25/CU;
// every K-step pays a full vmcnt(0)+barrier drain with too few co-resident
// waves to hide it). New loop: stage(next) issued BEFORE compute(cur), one
// barrier per K-step -> staging latency hides under ds_read+MFMA.
// Also: MODE 7 split-K 16->32 combos (was 1 block/CU), part moves to alias
// dead ykv/ykvln (fits verified ws >= 232914944); reduce_sc grid 144->576.
//
// gemm_bt: C = A(MxK) * Bt(NxK)^T, 128x128 tile, BK=32, 4 waves x (4x4)
// mfma_f32_16x16x32_bf16, fp32 accum. global_load_lds(16B) staging.
// Layouts (learn_hip m89/m91):
//   A: lane m=l%16, k=8*(l/16)+e ; B: lane n=l%16, k=8*(l/16)+e
//   D: lane reg r: row=4*(l/16)+r, col=l%16
// ---------------------------------------------------------------------------

typedef __bf16 bf16;
typedef bf16  bf16x8 __attribute__((ext_vector_type(8)));
typedef float f32x4  __attribute__((ext_vector_type(4)));

#define BM 128
#define BN 128
#define BK 32
#define SW 32   // unpadded: required for global_load_lds lane-contiguity

typedef __attribute__((address_space(3))) unsigned int lds_uint;
typedef const __attribute__((address_space(1))) unsigned int glb_uint;

__device__ __forceinline__ void ld_g2l16(const void* g, void* l) {
  __builtin_amdgcn_global_load_lds((glb_uint*)g, (lds_uint*)l, 16, 0, 0);
}

__device__ __forceinline__ float block_sum256(float v) {
  __shared__ float sb[4];
#pragma unroll
  for (int o = 32; o > 0; o >>= 1) v += __shfl_down(v, o);
  __syncthreads();
  if ((threadIdx.x & 63) == 0) sb[threadIdx.x >> 6] = v;
  __syncthreads();
  return sb[0] + sb[1] + sb[2] + sb[3];
}

// MODE 1: relu -> xs(bf16, Cv); fused rope (inline sincos) -> qr(bf16, Dv)
// MODE 2: strict causal mask, bf16 store; tiles above diagonal skipped [fallback]
// MODE 3: fp32 store, K clamped to m0+BM (scores strictly causal)
// MODE 4: relu * xs(read Dv) -> xy bf16
// MODE 5: fp32 store (plain / split-K partial)
// MODE 6: scores split-K partial: grid(combo16, tile36), fp32 compact store
// MODE 7: dec split-K partial: grid(combo32, tile16); combo=head*8+chunk
// z-offset (MODE<6): ptr += (z&3)*aZ + (z>>2)*aZ2
template <int MODE>
__global__ __launch_bounds__(256) void gemm_bt(
    const bf16* __restrict__ A, long lda, long aZ, long aZ2,
    const bf16* __restrict__ Bt, long ldb, long bZ, long bZ2,
    void* __restrict__ Cv, long ldc, long cZ,
    void* __restrict__ Dv, long dZ,
    int M, int N, int K) {
  int m0, n0;
  long z = blockIdx.z;
  if (MODE == 6) {
    const int combo = blockIdx.x;   // head*4+slice, FASTEST -> same-XCD tiles
    const int tile  = blockIdx.y;   // 0..35 lower-tri tile
    const int tr = (int)((sqrtf(8.f * tile + 1.f) - 1.f) * 0.5f);
    const int tc = tile - tr * (tr + 1) / 2;
    m0 = tr * BM; n0 = tc * BN;
    A  += (long)(combo >> 2) * aZ2 + (long)(combo & 3) * aZ;
    Bt += (long)(combo >> 2) * bZ2 + (long)(combo & 3) * bZ;
  } else if (MODE == 7) {
    const int combo = blockIdx.x;   // head*8+chunk, FASTEST
    z = combo;
    m0 = (blockIdx.y >> 1) * BM;
    n0 = (blockIdx.y & 1) * BN;
    A  += (combo & 7) * aZ + (combo >> 3) * aZ2;
    Bt += (combo & 7) * bZ + (combo >> 3) * bZ2;
  } else {
    m0 = blockIdx.y * BM;
    n0 = blockIdx.x * BN;
    if (MODE == 2 && n0 > m0) return;  // never read downstream (MODE-3 K-clamp)
    A  += (z & 3) * aZ + (z >> 2) * aZ2;
    Bt += (z & 3) * bZ + (z >> 2) * bZ2;
  }

  // double-buffered: 2 x (8 KB A + 8 KB B) = 32 KB
  __shared__ __align__(16) bf16 As[2][BM * SW];
  __shared__ __align__(16) bf16 Bs[2][BN * SW];

  const int tid  = threadIdx.x;
  const int lane = tid & 63;
  const int wr   = (tid >> 6) >> 1;
  const int wc   = (tid >> 6) & 1;
  const int l15  = lane & 15;
  const int qd   = lane >> 4;

  f32x4 acc[4][4] = {};

  int Keff = K;
  if (MODE == 3) { int kc = m0 + BM; Keff = kc < K ? kc : K; }

  const int srow = tid >> 2;        // 0..63
  const int skc  = (tid & 3) * 8;   // 0,8,16,24 (elements)
  const bf16* ap = A + (long)(m0 + srow) * lda + skc;
  const bf16* bp = Bt + (long)(n0 + srow) * ldb + skc;

  auto stage = [&](int buf, int k0) {
    char* AsB = (char*)&As[buf][0];
    char* BsB = (char*)&Bs[buf][0];
    ld_g2l16(ap + k0,            AsB + tid * 16);         // A rows 0..63
    ld_g2l16(ap + k0 + 64 * lda, AsB + 4096 + tid * 16);  // A rows 64..127
    ld_g2l16(bp + k0,            BsB + tid * 16);         // B rows 0..63
    ld_g2l16(bp + k0 + 64 * ldb, BsB + 4096 + tid * 16);  // B rows 64..127
  };
  auto compute = [&](int buf) {
    bf16x8 af[4], bfr[4];
#pragma unroll
    for (int i = 0; i < 4; i++)
      af[i] = *(const bf16x8*)&As[buf][(wr * 64 + i * 16 + l15) * SW + qd * 8];
#pragma unroll
    for (int j = 0; j < 4; j++)
      bfr[j] = *(const bf16x8*)&Bs[buf][(wc * 64 + j * 16 + l15) * SW + qd * 8];
#pragma unroll
    for (int i = 0; i < 4; i++)
#pragma unroll
      for (int j = 0; j < 4; j++)
        acc[i][j] = __builtin_amdgcn_mfma_f32_16x16x32_bf16(af[i], bfr[j], acc[i][j], 0, 0, 0);
  };

  // T3 "minimum 2-phase": stage(next) issued BEFORE compute(cur); single
  // __syncthreads per K-step drains vmcnt(0) (next buf ready) and lgkmcnt
  // (cur buf reads retired, safe to overwrite at step+2).
  stage(0, 0);
  __syncthreads();
  int cur = 0;
  for (int k0 = BK; k0 < Keff; k0 += BK) {
    stage(cur ^ 1, k0);
    compute(cur);
    __syncthreads();
    cur ^= 1;
  }
  compute(cur);

#pragma unroll
  for (int i = 0; i < 4; i++) {
#pragma unroll
    for (int j = 0; j < 4; j++) {
#pragma unroll
      for (int r = 0; r < 4; r++) {
        const int row = m0 + wr * 64 + i * 16 + qd * 4 + r;
        const int col = n0 + wc * 64 + j * 16 + l15;
        float v = acc[i][j][r];
        if (MODE == 1) {
          float rv = fmaxf(v, 0.f);
          float pv = __shfl_xor(rv, 1);  // relu'd rope-pair partner (col^1, same row)
          ((bf16*)Cv)[z * cZ + (long)row * ldc + col] = (bf16)rv;
          // rope: p=col>>1, freq=2^(-p/256)/(2pi), phase=(t*freq mod 1)*2pi
          float freq = exp2f(-(float)(col >> 1) * (1.0f / 256.0f)) * 0.15915494309189535f;
          float ph = (float)row * freq;
          ph -= floorf(ph);
          float s, c;
          __sincosf(ph * 6.283185307179586f, &s, &c);
          float rot = (col & 1) ? pv : -pv;
          ((bf16*)Dv)[z * dZ + (long)row * ldc + col] = (bf16)(rv * c + rot * s);
        } else if (MODE == 2) {
          ((bf16*)Cv)[z * cZ + (long)row * ldc + col] = (bf16)((col < row) ? v : 0.f);
        } else if (MODE == 4) {
          float rv = fmaxf(v, 0.f);
          float xv = (float)((const bf16*)Dv)[z * dZ + (long)row * 8192 + col];
          ((bf16*)Cv)[z * cZ + (long)row * ldc + col] = (bf16)(rv * xv);
        } else if (MODE == 6) {
          const int combo = blockIdx.x;  // head*4+slice
          long base = (((long)(combo & 3) * 4 + (combo >> 2)) * 36 + blockIdx.y) * 16384;
          ((float*)Cv)[base + (long)(row - m0) * 128 + (col - n0)] = v;
        } else {  // 3, 5, 7
          ((float*)Cv)[z * cZ + (long)row * ldc + col] = v;
        }
      }
    }
  }
}

// sum 4 split-K slices, apply strict-causal mask, bf16 store into sc.
// scpart layout (from gemm_bt<6>): slice*2359296 + head*589824 + tile*16384.
// grid (36*4, 4): blockIdx.x = tile*4 + quarter (576 blocks for latency).
__global__ void reduce_sc(const float* __restrict__ scpart, bf16* __restrict__ sc) {
  const int tile = blockIdx.x >> 2, q = blockIdx.x & 3, head = blockIdx.y;
  const int tr = (int)((sqrtf(8.f * tile + 1.f) - 1.f) * 0.5f);
  const int tc = tile - tr * (tr + 1) / 2;
  const long t0 = (long)head * 589824 + (long)tile * 16384;
  const int i0 = q * 4096;
  for (int i = i0 + threadIdx.x; i < i0 + 4096; i += 256) {
    float s = scpart[t0 + i] + scpart[t0 + 2359296 + i]
            + scpart[t0 + 2L * 2359296 + i] + scpart[t0 + 3L * 2359296 + i];
    int lr = i >> 7, lc = i & 127;
    int grow = tr * 128 + lr, gcol = tc * 128 + lc;
    sc[(long)head * 1048576 + (long)grow * 1024 + gcol] = (bf16)((gcol < grow) ? s : 0.f);
  }
}

// out[c][r] = bf16(in[r][c]); fp32 input
__global__ void transpose_cvt(const float* __restrict__ in, bf16* __restrict__ out,
                              int R, int C, long inZ, long outZ) {
  in += (long)blockIdx.z * inZ;
  out += (long)blockIdx.z * outZ;
  __shared__ float tile[32][33];
  int c0 = blockIdx.x * 32, r0 = blockIdx.y * 32;
  int lc = threadIdx.x & 31, lr8 = threadIdx.x >> 5;
#pragma unroll
  for (int i = 0; i < 32; i += 8)
    tile[lr8 + i][lc] = in[(long)(r0 + lr8 + i) * C + c0 + lc];
  __syncthreads();
#pragma unroll
  for (int i = 0; i < 32; i += 8)
    out[(long)(c0 + lr8 + i) * R + r0 + lc] = (bf16)tile[lc][lr8 + i];
}

__global__ void embed_ln(const int* __restrict__ idx, const float* __restrict__ embed,
                         float* __restrict__ x, bf16* __restrict__ xb,
                         bf16* __restrict__ xT) {
  int t = blockIdx.x, d = threadIdx.x;
  float v = embed[(long)idx[t] * 256 + d];
  float m = block_sum256(v) * (1.0f / 256.0f);
  float c = v - m;
  float var = block_sum256(c * c) * (1.0f / 256.0f);
  float o = c * rsqrtf(var + 1e-5f);
  x[t * 256 + d] = o;
  xb[t * 256 + d] = (bf16)o;
  xT[d * 1024 + t] = (bf16)o;
}

__global__ void ln_rows(const float* __restrict__ in, bf16* __restrict__ out) {
  int r = blockIdx.x, d = threadIdx.x;
  float v = in[(long)r * 256 + d];
  float m = block_sum256(v) * (1.0f / 256.0f);
  float c = v - m;
  float var = block_sum256(c * c) * (1.0f / 256.0f);
  out[(long)r * 256 + d] = (bf16)(c * rsqrtf(var + 1e-5f));
}

__global__ void ln_fuse(const float* __restrict__ part, float* __restrict__ x,
                        bf16* __restrict__ xb, bf16* __restrict__ xT) {
  int t = blockIdx.x, d = threadIdx.x;
  float s = 0.f;
#pragma unroll
  for (int i = 0; i < 32; i++) s += part[(long)i * 262144 + t * 256 + d];
  float m = block_sum256(s) * (1.0f / 256.0f);
  float c = s - m;
  float var = block_sum256(c * c) * (1.0f / 256.0f);
  float y = c * rsqrtf(var + 1e-5f);
  float zv = x[t * 256 + d] + y;
  m = block_sum256(zv) * (1.0f / 256.0f);
  c = zv - m;
  var = block_sum256(c * c) * (1.0f / 256.0f);
  float o = c * rsqrtf(var + 1e-5f);
  x[t * 256 + d] = o;
  xb[t * 256 + d] = (bf16)o;
  xT[d * 1024 + t] = (bf16)o;
}

extern "C" void kernel_launch(void* const* d_in, const int* in_sizes, int n_in,
                              void* d_out, int out_size, void* d_ws, size_t ws_size,
                              hipStream_t stream) {
  const int*   idx = (const int*)d_in[0];
  const float* emb = (const float*)d_in[1];
  float* out = (float*)d_out;   // fp32 logits
  char* ws  = (char*)d_ws;

  // workspace layout (bytes)
  bf16*  encT   = (bf16*)(ws + 0L);            // (h,8192,256)
  bf16*  encvT  = (bf16*)(ws + 16777216L);     // (h,8192,256)
  bf16*  decT   = (bf16*)(ws + 33554432L);     // (256,32768)
  bf16*  lmT    = (bf16*)(ws + 50331648L);     // (256,256)
  float* x      = (float*)(ws + 50462720L);    // (1024,256) f32
  bf16*  xb     = (bf16*)(ws + 51511296L);     // (1024,256)
  bf16*  xT     = (bf16*)(ws + 52035584L);     // (256,1024)
  bf16*  xs     = (bf16*)(ws + 52559872L);     // (h,1024,8192)
  bf16*  qr     = (bf16*)(ws + 119668736L);    // (h,1024,8192); later xy
  bf16*  sc     = (bf16*)(ws + 186777600L);    // (h,1024,1024)
  // [195166208 .. 232914944): scpart (4 slices,4 heads,36 tiles,128,128) f32.
  // ykv/ykvln/part alias inside it — all dead while scpart is live.
  float* scpart = (float*)(ws + 195166208L);
  float* ykv    = (float*)(ws + 195166208L);   // (h,1024,256) f32
  bf16*  ykvln  = (bf16*)(ws + 199360512L);    // (h,1024,256)
  // part: (32,1024,256) f32 = 33.5 MB, starts at ykv (ykv/ykvln dead when
  // MODE-7 runs); ends at 228720640 < 232914944.
  float* part   = (float*)(ws + 195166208L);
  const bool big = ws_size >= 232914944UL;     // room for scpart?

  transpose_cvt<<<dim3(256, 8, 4), dim3(256), 0, stream>>>((const float*)d_in[2], encT, 256, 8192, 2097152L, 2097152L);
  transpose_cvt<<<dim3(256, 8, 4), dim3(256), 0, stream>>>((const float*)d_in[3], encvT, 256, 8192, 2097152L, 2097152L);
  transpose_cvt<<<dim3(8, 1024, 1), dim3(256), 0, stream>>>((const float*)d_in[4], decT, 32768, 256, 0L, 0L);
  transpose_cvt<<<dim3(8, 8, 1), dim3(256), 0, stream>>>((const float*)d_in[5], lmT, 256, 256, 0L, 0L);
  embed_ln<<<dim3(1024), dim3(256), 0, stream>>>(idx, emb, x, xb, xT);

  for (int l = 0; l < 6; l++) {
    // xs = relu(x @ encoder[h]); qr = rope(xs)   [fused epilogue]
    gemm_bt<1><<<dim3(64, 8, 4), dim3(256), 0, stream>>>(
        xb, 256L, 0L, 0L, encT, 256L, 2097152L, 8388608L,
        (void*)xs, 8192L, 8388608L, (void*)qr, 8388608L, 1024, 8192, 256);
    if (big) {
      // scores split-K x4, combo-fastest grid (XCD locality) -> reduce+mask
      gemm_bt<6><<<dim3(16, 36), dim3(256), 0, stream>>>(
          qr, 8192L, 2048L, 8388608L, qr, 8192L, 2048L, 8388608L,
          (void*)scpart, 0L, 0L, (void*)0, 0L, 1024, 1024, 2048);
      reduce_sc<<<dim3(144, 4), dim3(256), 0, stream>>>(scpart, sc);
    } else {
      gemm_bt<2><<<dim3(8, 8, 4), dim3(256), 0, stream>>>(
          qr, 8192L, 8388608L, 33554432L, qr, 8192L, 8388608L, 33554432L,
          (void*)sc, 1024L, 1048576L, (void*)0, 0L, 1024, 1024, 8192);
    }
    // ykv = sc @ x (fp32, K clamped to causal extent)
    gemm_bt<3><<<dim3(2, 8, 4), dim3(256), 0, stream>>>(
        sc, 1024L, 1048576L, 4194304L, xT, 1024L, 0L, 0L,
        (void*)ykv, 256L, 262144L, (void*)0, 0L, 1024, 256, 1024);
    ln_rows<<<dim3(4096), dim3(256), 0, stream>>>(ykv, ykvln);
    // xy = xs * relu(ykvln @ encoder_v[h]) -> qr (head-major)  [fused epilogue]
    gemm_bt<4><<<dim3(64, 8, 4), dim3(256), 0, stream>>>(
        ykvln, 256L, 262144L, 1048576L, encvT, 256L, 2097152L, 8388608L,
        (void*)qr, 8192L, 8388608L, (void*)xs, 8388608L, 1024, 8192, 256);
    // yMLP partials: split-K x8 per head (32 combos, 2 blocks/CU), combo-fastest
    gemm_bt<7><<<dim3(32, 16), dim3(256), 0, stream>>>(
        qr, 8192L, 1024L, 8388608L, decT, 32768L, 1024L, 8192L,
        (void*)part, 256L, 262144L, (void*)0, 0L, 1024, 256, 1024);
    ln_fuse<<<dim3(1024), dim3(256), 0, stream>>>(part, x, xb, xT);
  }
  // logits = x @ lm_head -> d_out (fp32)
  gemm_bt<5><<<dim3(2, 8, 1), dim3(256), 0, stream>>>(
      xb, 256L, 0L, 0L, lmT, 256L, 0L, 0L,
      (void*)out, 256L, 0L, (void*)0, 0L, 1024, 256, 256);
}

// Round 2
// 1473.199 us; speedup vs baseline: 1.1312x; 1.0081x over previous
//
#include <hip/hip_runtime.h>
#include <math.h>

// ---------------------------------------------------------------------------
// BDH forward, MI355X. Round 11 = round 10 + scores split-K x8 with bf16
// partials. Round-10 counters: MODE-6 at 21.6% MfmaUtil / 18% occupancy
// (576 blocks = 2.25 blocks/CU) => latency-bound; the 2-phase loop's barrier
// still drains vmcnt(0) and too few waves cover it. x8 split -> 1152 blocks
// = 4.5 blocks/CU. bf16 partials keep scpart in the same 37.7 MB region
// (8 x 4.7 MB) and cut reduce_sc read traffic 151 MB -> 37.7 MB (vectorized).
// Precision: partial magnitude ~ total/sqrt(8), so sqrt(8) bf16 roundings of
// partials ~ one extra bf16 rounding of the total (sc is already bf16).
//
// gemm_bt: C = A(MxK) * Bt(NxK)^T, 128x128 tile, BK=32, 4 waves x (4x4)
// mfma_f32_16x16x32_bf16, fp32 accum. global_load_lds(16B) staging,
// double-buffered LDS (stage(next) before compute(cur), 1 barrier/K-step).
// Layouts (learn_hip m89/m91):
//   A: lane m=l%16, k=8*(l/16)+e ; B: lane n=l%16, k=8*(l/16)+e
//   D: lane reg r: row=4*(l/16)+r, col=l%16
// ---------------------------------------------------------------------------

typedef __bf16 bf16;
typedef bf16  bf16x2 __attribute__((ext_vector_type(2)));
typedef bf16  bf16x8 __attribute__((ext_vector_type(8)));
typedef float f32x4  __attribute__((ext_vector_type(4)));

#define BM 128
#define BN 128
#define BK 32
#define SW 32   // unpadded: required for global_load_lds lane-contiguity

typedef __attribute__((address_space(3))) unsigned int lds_uint;
typedef const __attribute__((address_space(1))) unsigned int glb_uint;

__device__ __forceinline__ void ld_g2l16(const void* g, void* l) {
  __builtin_amdgcn_global_load_lds((glb_uint*)g, (lds_uint*)l, 16, 0, 0);
}

__device__ __forceinline__ float block_sum256(float v) {
  __shared__ float sb[4];
#pragma unroll
  for (int o = 32; o > 0; o >>= 1) v += __shfl_down(v, o);
  __syncthreads();
  if ((threadIdx.x & 63) == 0) sb[threadIdx.x >> 6] = v;
  __syncthreads();
  return sb[0] + sb[1] + sb[2] + sb[3];
}

// MODE 1: relu -> xs(bf16, Cv); fused rope (inline sincos) -> qr(bf16, Dv)
// MODE 2: strict causal mask, bf16 store; tiles above diagonal skipped [fallback]
// MODE 3: fp32 store, K clamped to m0+BM (scores strictly causal)
// MODE 4: relu * xs(read Dv) -> xy bf16
// MODE 5: fp32 store (plain / split-K partial)
// MODE 6: scores split-K x8 partial: grid(combo32, tile36), bf16 compact store
//         combo = head*8+slice -> XCD = combo%8 = slice (locality per XCD)
// MODE 7: dec split-K partial: grid(combo32, tile16); combo=head*8+chunk
// z-offset (MODE<6): ptr += (z&3)*aZ + (z>>2)*aZ2
template <int MODE>
__global__ __launch_bounds__(256) void gemm_bt(
    const bf16* __restrict__ A, long lda, long aZ, long aZ2,
    const bf16* __restrict__ Bt, long ldb, long bZ, long bZ2,
    void* __restrict__ Cv, long ldc, long cZ,
    void* __restrict__ Dv, long dZ,
    int M, int N, int K) {
  int m0, n0;
  long z = blockIdx.z;
  if (MODE == 6) {
    const int combo = blockIdx.x;   // head*8+slice, FASTEST -> XCD=slice
    const int tile  = blockIdx.y;   // 0..35 lower-tri tile
    const int tr = (int)((sqrtf(8.f * tile + 1.f) - 1.f) * 0.5f);
    const int tc = tile - tr * (tr + 1) / 2;
    m0 = tr * BM; n0 = tc * BN;
    A  += (long)(combo >> 3) * aZ2 + (long)(combo & 7) * aZ;
    Bt += (long)(combo >> 3) * bZ2 + (long)(combo & 7) * bZ;
  } else if (MODE == 7) {
    const int combo = blockIdx.x;   // head*8+chunk, FASTEST
    z = combo;
    m0 = (blockIdx.y >> 1) * BM;
    n0 = (blockIdx.y & 1) * BN;
    A  += (combo & 7) * aZ + (combo >> 3) * aZ2;
    Bt += (combo & 7) * bZ + (combo >> 3) * bZ2;
  } else {
    m0 = blockIdx.y * BM;
    n0 = blockIdx.x * BN;
    if (MODE == 2 && n0 > m0) return;  // never read downstream (MODE-3 K-clamp)
    A  += (z & 3) * aZ + (z >> 2) * aZ2;
    Bt += (z & 3) * bZ + (z >> 2) * bZ2;
  }

  // double-buffered: 2 x (8 KB A + 8 KB B) = 32 KB
  __shared__ __align__(16) bf16 As[2][BM * SW];
  __shared__ __align__(16) bf16 Bs[2][BN * SW];

  const int tid  = threadIdx.x;
  const int lane = tid & 63;
  const int wr   = (tid >> 6) >> 1;
  const int wc   = (tid >> 6) & 1;
  const int l15  = lane & 15;
  const int qd   = lane >> 4;

  f32x4 acc[4][4] = {};

  int Keff = K;
  if (MODE == 3) { int kc = m0 + BM; Keff = kc < K ? kc : K; }

  const int srow = tid >> 2;        // 0..63
  const int skc  = (tid & 3) * 8;   // 0,8,16,24 (elements)
  const bf16* ap = A + (long)(m0 + srow) * lda + skc;
  const bf16* bp = Bt + (long)(n0 + srow) * ldb + skc;

  auto stage = [&](int buf, int k0) {
    char* AsB = (char*)&As[buf][0];
    char* BsB = (char*)&Bs[buf][0];
    ld_g2l16(ap + k0,            AsB + tid * 16);         // A rows 0..63
    ld_g2l16(ap + k0 + 64 * lda, AsB + 4096 + tid * 16);  // A rows 64..127
    ld_g2l16(bp + k0,            BsB + tid * 16);         // B rows 0..63
    ld_g2l16(bp + k0 + 64 * ldb, BsB + 4096 + tid * 16);  // B rows 64..127
  };
  auto compute = [&](int buf) {
    bf16x8 af[4], bfr[4];
#pragma unroll
    for (int i = 0; i < 4; i++)
      af[i] = *(const bf16x8*)&As[buf][(wr * 64 + i * 16 + l15) * SW + qd * 8];
#pragma unroll
    for (int j = 0; j < 4; j++)
      bfr[j] = *(const bf16x8*)&Bs[buf][(wc * 64 + j * 16 + l15) * SW + qd * 8];
#pragma unroll
    for (int i = 0; i < 4; i++)
#pragma unroll
      for (int j = 0; j < 4; j++)
        acc[i][j] = __builtin_amdgcn_mfma_f32_16x16x32_bf16(af[i], bfr[j], acc[i][j], 0, 0, 0);
  };

  // T3 "minimum 2-phase": stage(next) issued BEFORE compute(cur); single
  // __syncthreads per K-step drains vmcnt(0) (next buf ready) and lgkmcnt
  // (cur buf reads retired, safe to overwrite at step+2).
  stage(0, 0);
  __syncthreads();
  int cur = 0;
  for (int k0 = BK; k0 < Keff; k0 += BK) {
    stage(cur ^ 1, k0);
    compute(cur);
    __syncthreads();
    cur ^= 1;
  }
  compute(cur);

#pragma unroll
  for (int i = 0; i < 4; i++) {
#pragma unroll
    for (int j = 0; j < 4; j++) {
#pragma unroll
      for (int r = 0; r < 4; r++) {
        const int row = m0 + wr * 64 + i * 16 + qd * 4 + r;
        const int col = n0 + wc * 64 + j * 16 + l15;
        float v = acc[i][j][r];
        if (MODE == 1) {
          float rv = fmaxf(v, 0.f);
          float pv = __shfl_xor(rv, 1);  // relu'd rope-pair partner (col^1, same row)
          ((bf16*)Cv)[z * cZ + (long)row * ldc + col] = (bf16)rv;
          // rope: p=col>>1, freq=2^(-p/256)/(2pi), phase=(t*freq mod 1)*2pi
          float freq = exp2f(-(float)(col >> 1) * (1.0f / 256.0f)) * 0.15915494309189535f;
          float ph = (float)row * freq;
          ph -= floorf(ph);
          float s, c;
          __sincosf(ph * 6.283185307179586f, &s, &c);
          float rot = (col & 1) ? pv : -pv;
          ((bf16*)Dv)[z * dZ + (long)row * ldc + col] = (bf16)(rv * c + rot * s);
        } else if (MODE == 2) {
          ((bf16*)Cv)[z * cZ + (long)row * ldc + col] = (bf16)((col < row) ? v : 0.f);
        } else if (MODE == 4) {
          float rv = fmaxf(v, 0.f);
          float xv = (float)((const bf16*)Dv)[z * dZ + (long)row * 8192 + col];
          ((bf16*)Cv)[z * cZ + (long)row * ldc + col] = (bf16)(rv * xv);
        } else if (MODE == 6) {
          const int combo = blockIdx.x;  // head*8+slice
          long base = (((long)(combo & 7) * 4 + (combo >> 3)) * 36 + blockIdx.y) * 16384;
          ((bf16*)Cv)[base + (long)(row - m0) * 128 + (col - n0)] = (bf16)v;
        } else {  // 3, 5, 7
          ((float*)Cv)[z * cZ + (long)row * ldc + col] = v;
        }
      }
    }
  }
}

// sum 8 bf16 split-K slices, apply strict-causal mask, bf16 store into sc.
// scpart layout (from gemm_bt<6>): (slice*4+head)*589824 + tile*16384, bf16.
// grid (36*4, 4): blockIdx.x = tile*4 + quarter; ushort2-vectorized loads.
__global__ void reduce_sc(const bf16* __restrict__ scpart, bf16* __restrict__ sc) {
  const int tile = blockIdx.x >> 2, q = blockIdx.x & 3, head = blockIdx.y;
  const int tr = (int)((sqrtf(8.f * tile + 1.f) - 1.f) * 0.5f);
  const int tc = tile - tr * (tr + 1) / 2;
  const long t0p = ((long)head * 589824 + (long)tile * 16384) >> 1;  // pair idx
  const bf16x2* sp = (const bf16x2*)scpart;
  for (int p = q * 2048 + threadIdx.x; p < q * 2048 + 2048; p += 256) {
    float s0 = 0.f, s1 = 0.f;
#pragma unroll
    for (int s = 0; s < 8; s++) {
      bf16x2 v = sp[(long)s * 1179648 + t0p + p];
      s0 += (float)v.x; s1 += (float)v.y;
    }
    int i = p * 2;
    int lr = i >> 7, lc = i & 127;
    int grow = tr * 128 + lr, gcol = tc * 128 + lc;
    bf16x2 o;
    o.x = (bf16)((gcol < grow) ? s0 : 0.f);
    o.y = (bf16)((gcol + 1 < grow) ? s1 : 0.f);
    *(bf16x2*)&sc[(long)head * 1048576 + (long)grow * 1024 + gcol] = o;
  }
}

// out[c][r] = bf16(in[r][c]); fp32 input
__global__ void transpose_cvt(const float* __restrict__ in, bf16* __restrict__ out,
                              int R, int C, long inZ, long outZ) {
  in += (long)blockIdx.z * inZ;
  out += (long)blockIdx.z * outZ;
  __shared__ float tile[32][33];
  int c0 = blockIdx.x * 32, r0 = blockIdx.y * 32;
  int lc = threadIdx.x & 31, lr8 = threadIdx.x >> 5;
#pragma unroll
  for (int i = 0; i < 32; i += 8)
    tile[lr8 + i][lc] = in[(long)(r0 + lr8 + i) * C + c0 + lc];
  __syncthreads();
#pragma unroll
  for (int i = 0; i < 32; i += 8)
    out[(long)(c0 + lr8 + i) * R + r0 + lc] = (bf16)tile[lc][lr8 + i];
}

__global__ void embed_ln(const int* __restrict__ idx, const float* __restrict__ embed,
                         float* __restrict__ x, bf16* __restrict__ xb,
                         bf16* __restrict__ xT) {
  int t = blockIdx.x, d = threadIdx.x;
  float v = embed[(long)idx[t] * 256 + d];
  float m = block_sum256(v) * (1.0f / 256.0f);
  float c = v - m;
  float var = block_sum256(c * c) * (1.0f / 256.0f);
  float o = c * rsqrtf(var + 1e-5f);
  x[t * 256 + d] = o;
  xb[t * 256 + d] = (bf16)o;
  xT[d * 1024 + t] = (bf16)o;
}

__global__ void ln_rows(const float* __restrict__ in, bf16* __restrict__ out) {
  int r = blockIdx.x, d = threadIdx.x;
  float v = in[(long)r * 256 + d];
  float m = block_sum256(v) * (1.0f / 256.0f);
  float c = v - m;
  float var = block_sum256(c * c) * (1.0f / 256.0f);
  out[(long)r * 256 + d] = (bf16)(c * rsqrtf(var + 1e-5f));
}

__global__ void ln_fuse(const float* __restrict__ part, float* __restrict__ x,
                        bf16* __restrict__ xb, bf16* __restrict__ xT) {
  int t = blockIdx.x, d = threadIdx.x;
  float s = 0.f;
#pragma unroll
  for (int i = 0; i < 32; i++) s += part[(long)i * 262144 + t * 256 + d];
  float m = block_sum256(s) * (1.0f / 256.0f);
  float c = s - m;
  float var = block_sum256(c * c) * (1.0f / 256.0f);
  float y = c * rsqrtf(var + 1e-5f);
  float zv = x[t * 256 + d] + y;
  m = block_sum256(zv) * (1.0f / 256.0f);
  c = zv - m;
  var = block_sum256(c * c) * (1.0f / 256.0f);
  float o = c * rsqrtf(var + 1e-5f);
  x[t * 256 + d] = o;
  xb[t * 256 + d] = (bf16)o;
  xT[d * 1024 + t] = (bf16)o;
}

extern "C" void kernel_launch(void* const* d_in, const int* in_sizes, int n_in,
                              void* d_out, int out_size, void* d_ws, size_t ws_size,
                              hipStream_t stream) {
  const int*   idx = (const int*)d_in[0];
  const float* emb = (const float*)d_in[1];
  float* out = (float*)d_out;   // fp32 logits
  char* ws  = (char*)d_ws;

  // workspace layout (bytes)
  bf16*  encT   = (bf16*)(ws + 0L);            // (h,8192,256)
  bf16*  encvT  = (bf16*)(ws + 16777216L);     // (h,8192,256)
  bf16*  decT   = (bf16*)(ws + 33554432L);     // (256,32768)
  bf16*  lmT    = (bf16*)(ws + 50331648L);     // (256,256)
  float* x      = (float*)(ws + 50462720L);    // (1024,256) f32
  bf16*  xb     = (bf16*)(ws + 51511296L);     // (1024,256)
  bf16*  xT     = (bf16*)(ws + 52035584L);     // (256,1024)
  bf16*  xs     = (bf16*)(ws + 52559872L);     // (h,1024,8192)
  bf16*  qr     = (bf16*)(ws + 119668736L);    // (h,1024,8192); later xy
  bf16*  sc     = (bf16*)(ws + 186777600L);    // (h,1024,1024)
  // [195166208 .. 232914944): scpart (8 slices,4 heads,36 tiles,128,128) bf16
  // = 37748736 B, ends exactly at 232914944. ykv/ykvln/part alias inside it —
  // all dead while scpart is live.
  bf16*  scpart = (bf16*)(ws + 195166208L);
  float* ykv    = (float*)(ws + 195166208L);   // (h,1024,256) f32
  bf16*  ykvln  = (bf16*)(ws + 199360512L);    // (h,1024,256)
  // part: (32,1024,256) f32 = 33.5 MB, starts at ykv (ykv/ykvln dead when
  // MODE-7 runs); ends at 228720640 < 232914944.
  float* part   = (float*)(ws + 195166208L);
  const bool big = ws_size >= 232914944UL;     // room for scpart?

  transpose_cvt<<<dim3(256, 8, 4), dim3(256), 0, stream>>>((const float*)d_in[2], encT, 256, 8192, 2097152L, 2097152L);
  transpose_cvt<<<dim3(256, 8, 4), dim3(256), 0, stream>>>((const float*)d_in[3], encvT, 256, 8192, 2097152L, 2097152L);
  transpose_cvt<<<dim3(8, 1024, 1), dim3(256), 0, stream>>>((const float*)d_in[4], decT, 32768, 256, 0L, 0L);
  transpose_cvt<<<dim3(8, 8, 1), dim3(256), 0, stream>>>((const float*)d_in[5], lmT, 256, 256, 0L, 0L);
  embed_ln<<<dim3(1024), dim3(256), 0, stream>>>(idx, emb, x, xb, xT);

  for (int l = 0; l < 6; l++) {
    // xs = relu(x @ encoder[h]); qr = rope(xs)   [fused epilogue]
    gemm_bt<1><<<dim3(64, 8, 4), dim3(256), 0, stream>>>(
        xb, 256L, 0L, 0L, encT, 256L, 2097152L, 8388608L,
        (void*)xs, 8192L, 8388608L, (void*)qr, 8388608L, 1024, 8192, 256);
    if (big) {
      // scores split-K x8 (bf16 partials), combo-fastest grid (XCD=slice)
      gemm_bt<6><<<dim3(32, 36), dim3(256), 0, stream>>>(
          qr, 8192L, 1024L, 8388608L, qr, 8192L, 1024L, 8388608L,
          (void*)scpart, 0L, 0L, (void*)0, 0L, 1024, 1024, 1024);
      reduce_sc<<<dim3(144, 4), dim3(256), 0, stream>>>(scpart, sc);
    } else {
      gemm_bt<2><<<dim3(8, 8, 4), dim3(256), 0, stream>>>(
          qr, 8192L, 8388608L, 33554432L, qr, 8192L, 8388608L, 33554432L,
          (void*)sc, 1024L, 1048576L, (void*)0, 0L, 1024, 1024, 8192);
    }
    // ykv = sc @ x (fp32, K clamped to causal extent)
    gemm_bt<3><<<dim3(2, 8, 4), dim3(256), 0, stream>>>(
        sc, 1024L, 1048576L, 4194304L, xT, 1024L, 0L, 0L,
        (void*)ykv, 256L, 262144L, (void*)0, 0L, 1024, 256, 1024);
    ln_rows<<<dim3(4096), dim3(256), 0, stream>>>(ykv, ykvln);
    // xy = xs * relu(ykvln @ encoder_v[h]) -> qr (head-major)  [fused epilogue]
    gemm_bt<4><<<dim3(64, 8, 4), dim3(256), 0, stream>>>(
        ykvln, 256L, 262144L, 1048576L, encvT, 256L, 2097152L, 8388608L,
        (void*)qr, 8192L, 8388608L, (void*)xs, 8388608L, 1024, 8192, 256);
    // yMLP partials: split-K x8 per head (32 combos, 2 blocks/CU), combo-fastest
    gemm_bt<7><<<dim3(32, 16), dim3(256), 0, stream>>>(
        qr, 8192L, 1024L, 8388608L, decT, 32768L, 1024L, 8192L,
        (void*)part, 256L, 262144L, (void*)0, 0L, 1024, 256, 1024);
    ln_fuse<<<dim3(1024), dim3(256), 0, stream>>>(part, x, xb, xT);
  }
  // logits = x @ lm_head -> d_out (fp32)
  gemm_bt<5><<<dim3(2, 8, 1), dim3(256), 0, stream>>>(
      xb, 256L, 0L, 0L, lmT, 256L, 0L, 0L,
      (void*)out, 256L, 0L, (void*)0, 0L, 1024, 256, 256);
}